// Round 1
// 9864.429 us; speedup vs baseline: 4.9220x; 4.9220x over previous
//
#include <hip/hip_runtime.h>
#include <cmath>

// Fused window attention w/ view-aware RoPE, fp32 baseline.
// One block per window (B=4096 blocks, 512 threads). Zero workspace.
// LDS: q/k/v head tiles + rope tables + 17KB scratch shared by
// (phaseA weight staging | softmax matrix | proj-weight transpose).
//
// R1 change: __launch_bounds__(512,4) had capped the kernel at 64 VGPRs
// (8 waves/SIMD), forcing accE/qv spills to scratch -> 116 GB of scratch
// WRITE traffic, VALUBusy 5%. Relax to (512,2): VGPR cap 128+, live set
// (~110) fits, zero spill. LDS (52KB) still allows 2-3 blocks/CU.

namespace {

constexpr int kN = 64;    // tokens per window
constexpr int kC = 256;   // channels
constexpr int kH = 8;     // heads
constexpr float kMaxLogit = 4.6051701859880913680f;  // log(100)
constexpr int NT = 512;

__device__ __forceinline__ float dot4(const float4 a, const float4 b) {
  return fmaf(a.x, b.x, fmaf(a.y, b.y, fmaf(a.z, b.z, a.w * b.w)));
}

__global__ __launch_bounds__(NT, 2) void fused_window_attn(
    const float* __restrict__ x, const float* __restrict__ mask,
    const float* __restrict__ qkv_w, const float* __restrict__ qkv_b,
    const float* __restrict__ proj_w, const float* __restrict__ proj_b,
    const float* __restrict__ logit_scale, float* __restrict__ out) {

  // pads chosen for 16B alignment + bank spread (see session notes)
  __shared__ float s_q[64][36];
  __shared__ float s_k[64][36];
  __shared__ float s_v[64][36];
  __shared__ float s_cs[64][16];
  __shared__ float s_sn[64][16];
  __shared__ float s_scr[64 * 68];  // union: wS[96][36]=3456 | S[64][68]=4352 | pwT[16][256]=4096

  const int b = blockIdx.x;
  const int tid = threadIdx.x;
  const int win = b & 63;  // b = g*64 + w  ->  mask window index
  const float* xb = x + (size_t)b * (kN * kC);

  const int cg = tid & 31;  // phase A: qkv dim; phase E: col quad
  const int rg = tid >> 5;  // 16 groups of 4 rows

  // ---- output accumulators (rows 4rg+i, cols {4cg+j, 128+4cg+j}), init = bias ----
  float accE[4][8];
  {
    const float4 blo = *(const float4*)(proj_b + 4 * cg);
    const float4 bhi = *(const float4*)(proj_b + 128 + 4 * cg);
#pragma unroll
    for (int i = 0; i < 4; ++i) {
      accE[i][0] = blo.x; accE[i][1] = blo.y; accE[i][2] = blo.z; accE[i][3] = blo.w;
      accE[i][4] = bhi.x; accE[i][5] = bhi.y; accE[i][6] = bhi.z; accE[i][7] = bhi.w;
    }
  }

  // ---- rope tables: angle = (n + VIEW_ID*VIEW_OFFSET) * 10000^(-i/16) ----
  for (int it = tid; it < 64 * 16; it += NT) {
    const int r = it >> 4, ii = it & 15;
    const float inv = expf(-0.575646273248511421f * (float)ii);  // log(10000)/16
    const float ang = ((float)r + 0.1f) * inv;
    s_cs[r][ii] = cosf(ang);
    s_sn[r][ii] = sinf(ang);
  }
  __syncthreads();

  const int n = tid >> 3;   // phase C/D row
  const int ms = tid & 7;   // phase C col-slot
  const int d0 = (tid & 7) * 4;  // phase D dim quad

  for (int hh = 0; hh < kH; ++hh) {
    // ================= Phase A: qkv = x @ Wqkv[head]^T =================
    float accA[4][3];
#pragma unroll
    for (int i = 0; i < 4; ++i)
#pragma unroll
      for (int j = 0; j < 3; ++j) accA[i][j] = 0.f;

    for (int kc = 0; kc < 8; ++kc) {
      __syncthreads();  // scratch reuse fence
      // stage 96 weight rows (q,k,v of this head) x 32-k chunk -> wS[96][36]
      for (int m = tid; m < 96 * 8; m += NT) {
        const int wr = m >> 3, c4 = m & 7;
        const int comp = wr >> 5, dim = wr & 31;
        const float4 wv = *(const float4*)(qkv_w + ((size_t)(comp * 256 + hh * 32 + dim) * 256 + kc * 32 + c4 * 4));
        *(float4*)(&s_scr[wr * 36 + c4 * 4]) = wv;
      }
      __syncthreads();
#pragma unroll
      for (int k4 = 0; k4 < 8; ++k4) {
        float4 xv[4];
#pragma unroll
        for (int i = 0; i < 4; ++i)
          xv[i] = *(const float4*)(xb + (4 * rg + i) * kC + kc * 32 + k4 * 4);
        float4 wv[3];
#pragma unroll
        for (int j = 0; j < 3; ++j)
          wv[j] = *(const float4*)(&s_scr[(32 * j + cg) * 36 + k4 * 4]);
#pragma unroll
        for (int i = 0; i < 4; ++i)
#pragma unroll
          for (int j = 0; j < 3; ++j) accA[i][j] += dot4(xv[i], wv[j]);
      }
    }
    // bias + park q/k/v in LDS (lanes cg -> conflict-free with pad 36? (36r+cg): cg distinct)
#pragma unroll
    for (int i = 0; i < 4; ++i) {
      s_q[4 * rg + i][cg] = accA[i][0] + qkv_b[0 * 256 + hh * 32 + cg];
      s_k[4 * rg + i][cg] = accA[i][1] + qkv_b[1 * 256 + hh * 32 + cg];
      s_v[4 * rg + i][cg] = accA[i][2] + qkv_b[2 * 256 + hh * 32 + cg];
    }
    __syncthreads();

    // ================= Phase B: RoPE (half-split) + L2 normalize =================
    for (int it = tid; it < 2048; it += NT) {
      const int buf = it >> 10;
      const int r = (it >> 4) & 63;
      const int ii = it & 15;
      float (*p)[36] = buf ? s_k : s_q;
      const float a = p[r][ii], b2 = p[r][ii + 16];
      const float c = s_cs[r][ii], s = s_sn[r][ii];
      p[r][ii] = a * c - b2 * s;
      p[r][ii + 16] = a * s + b2 * c;
    }
    __syncthreads();
    if (tid < 256) {
      const int rt = tid >> 1, half = tid & 1;
      float (*p)[36] = (rt >= 64) ? s_k : s_q;
      const int r = rt & 63;
      float ss = 0.f;
#pragma unroll
      for (int d = 16 * half; d < 16 * half + 16; ++d) ss = fmaf(p[r][d], p[r][d], ss);
      ss += __shfl_xor(ss, 1);
      const float scl = 1.0f / fmaxf(sqrtf(ss), 1e-12f);
#pragma unroll
      for (int d = 16 * half; d < 16 * half + 16; ++d) p[r][d] *= scl;
    }
    __syncthreads();

    // ================= Phase C: logits + softmax -> S in scratch =================
    const float sc_h = __expf(fminf(logit_scale[hh], kMaxLogit));
    float4 qv[8];
#pragma unroll
    for (int d4 = 0; d4 < 8; ++d4) qv[d4] = *(const float4*)(&s_q[n][d4 * 4]);
    float p8[8];
    float mx = -1e30f;
#pragma unroll
    for (int j = 0; j < 8; ++j) {
      const int m = ms + 8 * j;  // stride-8 map: k-row LDS addrs spread over banks
      float a = 0.f;
#pragma unroll
      for (int d4 = 0; d4 < 8; ++d4) a += dot4(qv[d4], *(const float4*)(&s_k[m][d4 * 4]));
      a = fmaf(a, sc_h, mask[(size_t)win * 4096 + n * 64 + m]);
      p8[j] = a;
      mx = fmaxf(mx, a);
    }
    mx = fmaxf(mx, __shfl_xor(mx, 1));
    mx = fmaxf(mx, __shfl_xor(mx, 2));
    mx = fmaxf(mx, __shfl_xor(mx, 4));
    float sm = 0.f;
#pragma unroll
    for (int j = 0; j < 8; ++j) { p8[j] = __expf(p8[j] - mx); sm += p8[j]; }
    sm += __shfl_xor(sm, 1);
    sm += __shfl_xor(sm, 2);
    sm += __shfl_xor(sm, 4);
    const float rinv = 1.0f / sm;
#pragma unroll
    for (int j = 0; j < 8; ++j) s_scr[n * 68 + ms + 8 * j] = p8[j] * rinv;
    __syncthreads();

    // ================= Phase D: attn_h = P @ V  (result -> s_q) =================
    float4 o4 = {0.f, 0.f, 0.f, 0.f};
#pragma unroll
    for (int m4 = 0; m4 < 16; ++m4) {
      const float4 pv = *(const float4*)(&s_scr[n * 68 + m4 * 4]);
      const float4 v0 = *(const float4*)(&s_v[m4 * 4 + 0][d0]);
      const float4 v1 = *(const float4*)(&s_v[m4 * 4 + 1][d0]);
      const float4 v2 = *(const float4*)(&s_v[m4 * 4 + 2][d0]);
      const float4 v3 = *(const float4*)(&s_v[m4 * 4 + 3][d0]);
      o4.x = fmaf(pv.x, v0.x, o4.x); o4.y = fmaf(pv.x, v0.y, o4.y); o4.z = fmaf(pv.x, v0.z, o4.z); o4.w = fmaf(pv.x, v0.w, o4.w);
      o4.x = fmaf(pv.y, v1.x, o4.x); o4.y = fmaf(pv.y, v1.y, o4.y); o4.z = fmaf(pv.y, v1.z, o4.z); o4.w = fmaf(pv.y, v1.w, o4.w);
      o4.x = fmaf(pv.z, v2.x, o4.x); o4.y = fmaf(pv.z, v2.y, o4.y); o4.z = fmaf(pv.z, v2.z, o4.z); o4.w = fmaf(pv.z, v2.w, o4.w);
      o4.x = fmaf(pv.w, v3.x, o4.x); o4.y = fmaf(pv.w, v3.y, o4.y); o4.z = fmaf(pv.w, v3.z, o4.z); o4.w = fmaf(pv.w, v3.w, o4.w);
    }
    *(float4*)(&s_q[n][d0]) = o4;  // s_q now holds attn_h
    __syncthreads();

    // ================= Phase E: out += attn_h @ proj_w[:, head]^T =================
    for (int dc = 0; dc < 2; ++dc) {
      __syncthreads();  // prior scratch readers done (dc=0: phase D; dc=1: previous chunk)
      for (int m = tid; m < 1024; m += NT) {
        const int c = m >> 2, dd4 = m & 3;
        const float4 v = *(const float4*)(proj_w + (size_t)c * 256 + hh * 32 + dc * 16 + dd4 * 4);
        s_scr[(dd4 * 4 + 0) * 256 + c] = v.x;
        s_scr[(dd4 * 4 + 1) * 256 + c] = v.y;
        s_scr[(dd4 * 4 + 2) * 256 + c] = v.z;
        s_scr[(dd4 * 4 + 3) * 256 + c] = v.w;
      }
      __syncthreads();
#pragma unroll
      for (int d4 = 0; d4 < 4; ++d4) {
        float4 a4[4];
#pragma unroll
        for (int i = 0; i < 4; ++i) a4[i] = *(const float4*)(&s_q[4 * rg + i][dc * 16 + d4 * 4]);
#pragma unroll
        for (int kk = 0; kk < 4; ++kk) {
          const int dd = d4 * 4 + kk;
          const float4 wlo = *(const float4*)(&s_scr[dd * 256 + 4 * cg]);
          const float4 whi = *(const float4*)(&s_scr[dd * 256 + 128 + 4 * cg]);
#pragma unroll
          for (int i = 0; i < 4; ++i) {
            const float av = (kk == 0) ? a4[i].x : (kk == 1) ? a4[i].y : (kk == 2) ? a4[i].z : a4[i].w;
            accE[i][0] = fmaf(av, wlo.x, accE[i][0]);
            accE[i][1] = fmaf(av, wlo.y, accE[i][1]);
            accE[i][2] = fmaf(av, wlo.z, accE[i][2]);
            accE[i][3] = fmaf(av, wlo.w, accE[i][3]);
            accE[i][4] = fmaf(av, whi.x, accE[i][4]);
            accE[i][5] = fmaf(av, whi.y, accE[i][5]);
            accE[i][6] = fmaf(av, whi.z, accE[i][6]);
            accE[i][7] = fmaf(av, whi.w, accE[i][7]);
          }
        }
      }
    }
    __syncthreads();  // end-of-head fence before next phase A overwrites LDS
  }

  // ---- final store (fully overwrites d_out) ----
  float* ob = out + (size_t)b * (kN * kC);
#pragma unroll
  for (int i = 0; i < 4; ++i) {
    const float4 lo = {accE[i][0], accE[i][1], accE[i][2], accE[i][3]};
    const float4 hi = {accE[i][4], accE[i][5], accE[i][6], accE[i][7]};
    *(float4*)(&ob[(4 * rg + i) * 256 + 4 * cg]) = lo;
    *(float4*)(&ob[(4 * rg + i) * 256 + 128 + 4 * cg]) = hi;
  }
}

}  // namespace

extern "C" void kernel_launch(void* const* d_in, const int* in_sizes, int n_in,
                              void* d_out, int out_size, void* d_ws, size_t ws_size,
                              hipStream_t stream) {
  (void)n_in; (void)d_ws; (void)ws_size; (void)out_size;
  const float* x = (const float*)d_in[0];
  const float* mask = (const float*)d_in[1];
  const float* qkv_w = (const float*)d_in[2];
  const float* qkv_b = (const float*)d_in[3];
  const float* proj_w = (const float*)d_in[4];
  const float* proj_b = (const float*)d_in[5];
  const float* lsc = (const float*)d_in[6];
  float* out = (float*)d_out;

  const int nB = in_sizes[0] / (kN * kC);  // 4096
  dim3 grid(nB), block(NT);
  hipLaunchKernelGGL(fused_window_attn, grid, block, 0, stream,
                     x, mask, qkv_w, qkv_b, proj_w, proj_b, lsc, out);
}

// Round 2
// 9859.200 us; speedup vs baseline: 4.9246x; 1.0005x over previous
//
#include <hip/hip_runtime.h>
#include <cmath>

// Fused window attention w/ view-aware RoPE, fp32 baseline.
// One block per window (B=4096 blocks, 512 threads). Zero workspace.
// LDS: q/k/v head tiles + rope tables + 17KB scratch shared by
// (phaseA weight staging | softmax matrix | proj-weight transpose).
//
// R1: __launch_bounds__(512,4) capped at 64 VGPRs -> massive spill (116GB
//     scratch writes). (512,2) -> 128 cap: 48.5ms -> 9.9ms, but still
//     pinned at the cap with ~13GB residual spill traffic.
// R2: (512,1) -> 256 VGPR cap. Live set (~150-200) fits, zero spill.
//     Occupancy 8 waves/CU -- measured occupancy was already ~23%, so
//     no practical loss; all scratch HBM traffic disappears.

namespace {

constexpr int kN = 64;    // tokens per window
constexpr int kC = 256;   // channels
constexpr int kH = 8;     // heads
constexpr float kMaxLogit = 4.6051701859880913680f;  // log(100)
constexpr int NT = 512;

__device__ __forceinline__ float dot4(const float4 a, const float4 b) {
  return fmaf(a.x, b.x, fmaf(a.y, b.y, fmaf(a.z, b.z, a.w * b.w)));
}

__global__ __launch_bounds__(NT, 1) void fused_window_attn(
    const float* __restrict__ x, const float* __restrict__ mask,
    const float* __restrict__ qkv_w, const float* __restrict__ qkv_b,
    const float* __restrict__ proj_w, const float* __restrict__ proj_b,
    const float* __restrict__ logit_scale, float* __restrict__ out) {

  // pads chosen for 16B alignment + bank spread (see session notes)
  __shared__ float s_q[64][36];
  __shared__ float s_k[64][36];
  __shared__ float s_v[64][36];
  __shared__ float s_cs[64][16];
  __shared__ float s_sn[64][16];
  __shared__ float s_scr[64 * 68];  // union: wS[96][36]=3456 | S[64][68]=4352 | pwT[16][256]=4096

  const int b = blockIdx.x;
  const int tid = threadIdx.x;
  const int win = b & 63;  // b = g*64 + w  ->  mask window index
  const float* xb = x + (size_t)b * (kN * kC);

  const int cg = tid & 31;  // phase A: qkv dim; phase E: col quad
  const int rg = tid >> 5;  // 16 groups of 4 rows

  // ---- output accumulators (rows 4rg+i, cols {4cg+j, 128+4cg+j}), init = bias ----
  float accE[4][8];
  {
    const float4 blo = *(const float4*)(proj_b + 4 * cg);
    const float4 bhi = *(const float4*)(proj_b + 128 + 4 * cg);
#pragma unroll
    for (int i = 0; i < 4; ++i) {
      accE[i][0] = blo.x; accE[i][1] = blo.y; accE[i][2] = blo.z; accE[i][3] = blo.w;
      accE[i][4] = bhi.x; accE[i][5] = bhi.y; accE[i][6] = bhi.z; accE[i][7] = bhi.w;
    }
  }

  // ---- rope tables: angle = (n + VIEW_ID*VIEW_OFFSET) * 10000^(-i/16) ----
  for (int it = tid; it < 64 * 16; it += NT) {
    const int r = it >> 4, ii = it & 15;
    const float inv = expf(-0.575646273248511421f * (float)ii);  // log(10000)/16
    const float ang = ((float)r + 0.1f) * inv;
    s_cs[r][ii] = cosf(ang);
    s_sn[r][ii] = sinf(ang);
  }
  __syncthreads();

  const int n = tid >> 3;   // phase C/D row
  const int ms = tid & 7;   // phase C col-slot
  const int d0 = (tid & 7) * 4;  // phase D dim quad

  for (int hh = 0; hh < kH; ++hh) {
    // ================= Phase A: qkv = x @ Wqkv[head]^T =================
    float accA[4][3];
#pragma unroll
    for (int i = 0; i < 4; ++i)
#pragma unroll
      for (int j = 0; j < 3; ++j) accA[i][j] = 0.f;

    for (int kc = 0; kc < 8; ++kc) {
      __syncthreads();  // scratch reuse fence
      // stage 96 weight rows (q,k,v of this head) x 32-k chunk -> wS[96][36]
      for (int m = tid; m < 96 * 8; m += NT) {
        const int wr = m >> 3, c4 = m & 7;
        const int comp = wr >> 5, dim = wr & 31;
        const float4 wv = *(const float4*)(qkv_w + ((size_t)(comp * 256 + hh * 32 + dim) * 256 + kc * 32 + c4 * 4));
        *(float4*)(&s_scr[wr * 36 + c4 * 4]) = wv;
      }
      __syncthreads();
#pragma unroll
      for (int k4 = 0; k4 < 8; ++k4) {
        float4 xv[4];
#pragma unroll
        for (int i = 0; i < 4; ++i)
          xv[i] = *(const float4*)(xb + (4 * rg + i) * kC + kc * 32 + k4 * 4);
        float4 wv[3];
#pragma unroll
        for (int j = 0; j < 3; ++j)
          wv[j] = *(const float4*)(&s_scr[(32 * j + cg) * 36 + k4 * 4]);
#pragma unroll
        for (int i = 0; i < 4; ++i)
#pragma unroll
          for (int j = 0; j < 3; ++j) accA[i][j] += dot4(xv[i], wv[j]);
      }
    }
    // bias + park q/k/v in LDS (lanes cg -> conflict-free with pad 36? (36r+cg): cg distinct)
#pragma unroll
    for (int i = 0; i < 4; ++i) {
      s_q[4 * rg + i][cg] = accA[i][0] + qkv_b[0 * 256 + hh * 32 + cg];
      s_k[4 * rg + i][cg] = accA[i][1] + qkv_b[1 * 256 + hh * 32 + cg];
      s_v[4 * rg + i][cg] = accA[i][2] + qkv_b[2 * 256 + hh * 32 + cg];
    }
    __syncthreads();

    // ================= Phase B: RoPE (half-split) + L2 normalize =================
    for (int it = tid; it < 2048; it += NT) {
      const int buf = it >> 10;
      const int r = (it >> 4) & 63;
      const int ii = it & 15;
      float (*p)[36] = buf ? s_k : s_q;
      const float a = p[r][ii], b2 = p[r][ii + 16];
      const float c = s_cs[r][ii], s = s_sn[r][ii];
      p[r][ii] = a * c - b2 * s;
      p[r][ii + 16] = a * s + b2 * c;
    }
    __syncthreads();
    if (tid < 256) {
      const int rt = tid >> 1, half = tid & 1;
      float (*p)[36] = (rt >= 64) ? s_k : s_q;
      const int r = rt & 63;
      float ss = 0.f;
#pragma unroll
      for (int d = 16 * half; d < 16 * half + 16; ++d) ss = fmaf(p[r][d], p[r][d], ss);
      ss += __shfl_xor(ss, 1);
      const float scl = 1.0f / fmaxf(sqrtf(ss), 1e-12f);
#pragma unroll
      for (int d = 16 * half; d < 16 * half + 16; ++d) p[r][d] *= scl;
    }
    __syncthreads();

    // ================= Phase C: logits + softmax -> S in scratch =================
    const float sc_h = __expf(fminf(logit_scale[hh], kMaxLogit));
    float4 qv[8];
#pragma unroll
    for (int d4 = 0; d4 < 8; ++d4) qv[d4] = *(const float4*)(&s_q[n][d4 * 4]);
    float p8[8];
    float mx = -1e30f;
#pragma unroll
    for (int j = 0; j < 8; ++j) {
      const int m = ms + 8 * j;  // stride-8 map: k-row LDS addrs spread over banks
      float a = 0.f;
#pragma unroll
      for (int d4 = 0; d4 < 8; ++d4) a += dot4(qv[d4], *(const float4*)(&s_k[m][d4 * 4]));
      a = fmaf(a, sc_h, mask[(size_t)win * 4096 + n * 64 + m]);
      p8[j] = a;
      mx = fmaxf(mx, a);
    }
    mx = fmaxf(mx, __shfl_xor(mx, 1));
    mx = fmaxf(mx, __shfl_xor(mx, 2));
    mx = fmaxf(mx, __shfl_xor(mx, 4));
    float sm = 0.f;
#pragma unroll
    for (int j = 0; j < 8; ++j) { p8[j] = __expf(p8[j] - mx); sm += p8[j]; }
    sm += __shfl_xor(sm, 1);
    sm += __shfl_xor(sm, 2);
    sm += __shfl_xor(sm, 4);
    const float rinv = 1.0f / sm;
#pragma unroll
    for (int j = 0; j < 8; ++j) s_scr[n * 68 + ms + 8 * j] = p8[j] * rinv;
    __syncthreads();

    // ================= Phase D: attn_h = P @ V  (result -> s_q) =================
    float4 o4 = {0.f, 0.f, 0.f, 0.f};
#pragma unroll
    for (int m4 = 0; m4 < 16; ++m4) {
      const float4 pv = *(const float4*)(&s_scr[n * 68 + m4 * 4]);
      const float4 v0 = *(const float4*)(&s_v[m4 * 4 + 0][d0]);
      const float4 v1 = *(const float4*)(&s_v[m4 * 4 + 1][d0]);
      const float4 v2 = *(const float4*)(&s_v[m4 * 4 + 2][d0]);
      const float4 v3 = *(const float4*)(&s_v[m4 * 4 + 3][d0]);
      o4.x = fmaf(pv.x, v0.x, o4.x); o4.y = fmaf(pv.x, v0.y, o4.y); o4.z = fmaf(pv.x, v0.z, o4.z); o4.w = fmaf(pv.x, v0.w, o4.w);
      o4.x = fmaf(pv.y, v1.x, o4.x); o4.y = fmaf(pv.y, v1.y, o4.y); o4.z = fmaf(pv.y, v1.z, o4.z); o4.w = fmaf(pv.y, v1.w, o4.w);
      o4.x = fmaf(pv.z, v2.x, o4.x); o4.y = fmaf(pv.z, v2.y, o4.y); o4.z = fmaf(pv.z, v2.z, o4.z); o4.w = fmaf(pv.z, v2.w, o4.w);
      o4.x = fmaf(pv.w, v3.x, o4.x); o4.y = fmaf(pv.w, v3.y, o4.y); o4.z = fmaf(pv.w, v3.z, o4.z); o4.w = fmaf(pv.w, v3.w, o4.w);
    }
    *(float4*)(&s_q[n][d0]) = o4;  // s_q now holds attn_h
    __syncthreads();

    // ================= Phase E: out += attn_h @ proj_w[:, head]^T =================
    for (int dc = 0; dc < 2; ++dc) {
      __syncthreads();  // prior scratch readers done (dc=0: phase D; dc=1: previous chunk)
      for (int m = tid; m < 1024; m += NT) {
        const int c = m >> 2, dd4 = m & 3;
        const float4 v = *(const float4*)(proj_w + (size_t)c * 256 + hh * 32 + dc * 16 + dd4 * 4);
        s_scr[(dd4 * 4 + 0) * 256 + c] = v.x;
        s_scr[(dd4 * 4 + 1) * 256 + c] = v.y;
        s_scr[(dd4 * 4 + 2) * 256 + c] = v.z;
        s_scr[(dd4 * 4 + 3) * 256 + c] = v.w;
      }
      __syncthreads();
#pragma unroll
      for (int d4 = 0; d4 < 4; ++d4) {
        float4 a4[4];
#pragma unroll
        for (int i = 0; i < 4; ++i) a4[i] = *(const float4*)(&s_q[4 * rg + i][dc * 16 + d4 * 4]);
#pragma unroll
        for (int kk = 0; kk < 4; ++kk) {
          const int dd = d4 * 4 + kk;
          const float4 wlo = *(const float4*)(&s_scr[dd * 256 + 4 * cg]);
          const float4 whi = *(const float4*)(&s_scr[dd * 256 + 128 + 4 * cg]);
#pragma unroll
          for (int i = 0; i < 4; ++i) {
            const float av = (kk == 0) ? a4[i].x : (kk == 1) ? a4[i].y : (kk == 2) ? a4[i].z : a4[i].w;
            accE[i][0] = fmaf(av, wlo.x, accE[i][0]);
            accE[i][1] = fmaf(av, wlo.y, accE[i][1]);
            accE[i][2] = fmaf(av, wlo.z, accE[i][2]);
            accE[i][3] = fmaf(av, wlo.w, accE[i][3]);
            accE[i][4] = fmaf(av, whi.x, accE[i][4]);
            accE[i][5] = fmaf(av, whi.y, accE[i][5]);
            accE[i][6] = fmaf(av, whi.z, accE[i][6]);
            accE[i][7] = fmaf(av, whi.w, accE[i][7]);
          }
        }
      }
    }
    __syncthreads();  // end-of-head fence before next phase A overwrites LDS
  }

  // ---- final store (fully overwrites d_out) ----
  float* ob = out + (size_t)b * (kN * kC);
#pragma unroll
  for (int i = 0; i < 4; ++i) {
    const float4 lo = {accE[i][0], accE[i][1], accE[i][2], accE[i][3]};
    const float4 hi = {accE[i][4], accE[i][5], accE[i][6], accE[i][7]};
    *(float4*)(&ob[(4 * rg + i) * 256 + 4 * cg]) = lo;
    *(float4*)(&ob[(4 * rg + i) * 256 + 128 + 4 * cg]) = hi;
  }
}

}  // namespace

extern "C" void kernel_launch(void* const* d_in, const int* in_sizes, int n_in,
                              void* d_out, int out_size, void* d_ws, size_t ws_size,
                              hipStream_t stream) {
  (void)n_in; (void)d_ws; (void)ws_size; (void)out_size;
  const float* x = (const float*)d_in[0];
  const float* mask = (const float*)d_in[1];
  const float* qkv_w = (const float*)d_in[2];
  const float* qkv_b = (const float*)d_in[3];
  const float* proj_w = (const float*)d_in[4];
  const float* proj_b = (const float*)d_in[5];
  const float* lsc = (const float*)d_in[6];
  float* out = (float*)d_out;

  const int nB = in_sizes[0] / (kN * kC);  // 4096
  dim3 grid(nB), block(NT);
  hipLaunchKernelGGL(fused_window_attn, grid, block, 0, stream,
                     x, mask, qkv_w, qkv_b, proj_w, proj_b, lsc, out);
}

// Round 4
// 5204.164 us; speedup vs baseline: 9.3296x; 1.8945x over previous
//
#include <hip/hip_runtime.h>
#include <cmath>

// Fused window attention w/ view-aware RoPE, fp32 baseline.
// One block per window (B=4096 blocks, 512 threads). Zero workspace.
//
// R1: launch_bounds(512,4) -> 64-VGPR cap, 116GB spill writes. (512,2)
//     -> 128 cap: 48.5ms -> 9.9ms, 13GB residual spill.
// R2: (512,1) raised budget to 256 but NULL: allocator stayed at 128 +
//     spill. Diagnosis: full unrolling hoists whole load fronts (phase A
//     k4-loop alone ~224 VGPRs of in-flight float4) -> peak demand ~290
//     > 256 -> allocator gives up on fitting, targets occupancy, spills.
// R3: amdgpu_waves_per_eu attrs -> container failed (infra or compile).
// R4: same theory, conservative spelling: launch_bounds(512,1) (256-reg
//     budget, known-good) + unroll caps (k4->2, C.j->2, D.m4->4, E.d4->2)
//     so peak demand ~150 fits. Zero spill expected.

namespace {

constexpr int kN = 64;    // tokens per window
constexpr int kC = 256;   // channels
constexpr int kH = 8;     // heads
constexpr float kMaxLogit = 4.6051701859880913680f;  // log(100)
constexpr int NT = 512;

__device__ __forceinline__ float dot4(const float4 a, const float4 b) {
  return fmaf(a.x, b.x, fmaf(a.y, b.y, fmaf(a.z, b.z, a.w * b.w)));
}

__global__ __launch_bounds__(NT, 1) void fused_window_attn(
    const float* __restrict__ x, const float* __restrict__ mask,
    const float* __restrict__ qkv_w, const float* __restrict__ qkv_b,
    const float* __restrict__ proj_w, const float* __restrict__ proj_b,
    const float* __restrict__ logit_scale, float* __restrict__ out) {

  // pads chosen for 16B alignment + bank spread (see session notes)
  __shared__ float s_q[64][36];
  __shared__ float s_k[64][36];
  __shared__ float s_v[64][36];
  __shared__ float s_cs[64][16];
  __shared__ float s_sn[64][16];
  __shared__ float s_scr[64 * 68];  // union: wS[96][36]=3456 | S[64][68]=4352 | pwT[16][256]=4096

  const int b = blockIdx.x;
  const int tid = threadIdx.x;
  const int win = b & 63;  // b = g*64 + w  ->  mask window index
  const float* xb = x + (size_t)b * (kN * kC);

  const int cg = tid & 31;  // phase A: qkv dim; phase E: col quad
  const int rg = tid >> 5;  // 16 groups of 4 rows

  // ---- output accumulators (rows 4rg+i, cols {4cg+j, 128+4cg+j}), init = bias ----
  float accE[4][8];
  {
    const float4 blo = *(const float4*)(proj_b + 4 * cg);
    const float4 bhi = *(const float4*)(proj_b + 128 + 4 * cg);
#pragma unroll
    for (int i = 0; i < 4; ++i) {
      accE[i][0] = blo.x; accE[i][1] = blo.y; accE[i][2] = blo.z; accE[i][3] = blo.w;
      accE[i][4] = bhi.x; accE[i][5] = bhi.y; accE[i][6] = bhi.z; accE[i][7] = bhi.w;
    }
  }

  // ---- rope tables: angle = (n + VIEW_ID*VIEW_OFFSET) * 10000^(-i/16) ----
  for (int it = tid; it < 64 * 16; it += NT) {
    const int r = it >> 4, ii = it & 15;
    const float inv = expf(-0.575646273248511421f * (float)ii);  // log(10000)/16
    const float ang = ((float)r + 0.1f) * inv;
    s_cs[r][ii] = cosf(ang);
    s_sn[r][ii] = sinf(ang);
  }
  __syncthreads();

  const int n = tid >> 3;   // phase C/D row
  const int ms = tid & 7;   // phase C col-slot
  const int d0 = (tid & 7) * 4;  // phase D dim quad

  for (int hh = 0; hh < kH; ++hh) {
    // ================= Phase A: qkv = x @ Wqkv[head]^T =================
    float accA[4][3];
#pragma unroll
    for (int i = 0; i < 4; ++i)
#pragma unroll
      for (int j = 0; j < 3; ++j) accA[i][j] = 0.f;

    for (int kc = 0; kc < 8; ++kc) {
      __syncthreads();  // scratch reuse fence
      // stage 96 weight rows (q,k,v of this head) x 32-k chunk -> wS[96][36]
      for (int m = tid; m < 96 * 8; m += NT) {
        const int wr = m >> 3, c4 = m & 7;
        const int comp = wr >> 5, dim = wr & 31;
        const float4 wv = *(const float4*)(qkv_w + ((size_t)(comp * 256 + hh * 32 + dim) * 256 + kc * 32 + c4 * 4));
        *(float4*)(&s_scr[wr * 36 + c4 * 4]) = wv;
      }
      __syncthreads();
      // unroll 2: full unroll hoists 8x7 float4 loads (~224 VGPRs) -> spill
#pragma unroll 2
      for (int k4 = 0; k4 < 8; ++k4) {
        float4 xv[4];
#pragma unroll
        for (int i = 0; i < 4; ++i)
          xv[i] = *(const float4*)(xb + (4 * rg + i) * kC + kc * 32 + k4 * 4);
        float4 wv[3];
#pragma unroll
        for (int j = 0; j < 3; ++j)
          wv[j] = *(const float4*)(&s_scr[(32 * j + cg) * 36 + k4 * 4]);
#pragma unroll
        for (int i = 0; i < 4; ++i)
#pragma unroll
          for (int j = 0; j < 3; ++j) accA[i][j] += dot4(xv[i], wv[j]);
      }
    }
    // bias + park q/k/v in LDS (lanes cg -> conflict-free with pad 36? (36r+cg): cg distinct)
#pragma unroll
    for (int i = 0; i < 4; ++i) {
      s_q[4 * rg + i][cg] = accA[i][0] + qkv_b[0 * 256 + hh * 32 + cg];
      s_k[4 * rg + i][cg] = accA[i][1] + qkv_b[1 * 256 + hh * 32 + cg];
      s_v[4 * rg + i][cg] = accA[i][2] + qkv_b[2 * 256 + hh * 32 + cg];
    }
    __syncthreads();

    // ================= Phase B: RoPE (half-split) + L2 normalize =================
    for (int it = tid; it < 2048; it += NT) {
      const int buf = it >> 10;
      const int r = (it >> 4) & 63;
      const int ii = it & 15;
      float (*p)[36] = buf ? s_k : s_q;
      const float a = p[r][ii], b2 = p[r][ii + 16];
      const float c = s_cs[r][ii], s = s_sn[r][ii];
      p[r][ii] = a * c - b2 * s;
      p[r][ii + 16] = a * s + b2 * c;
    }
    __syncthreads();
    if (tid < 256) {
      const int rt = tid >> 1, half = tid & 1;
      float (*p)[36] = (rt >= 64) ? s_k : s_q;
      const int r = rt & 63;
      float ss = 0.f;
#pragma unroll
      for (int d = 16 * half; d < 16 * half + 16; ++d) ss = fmaf(p[r][d], p[r][d], ss);
      ss += __shfl_xor(ss, 1);
      const float scl = 1.0f / fmaxf(sqrtf(ss), 1e-12f);
#pragma unroll
      for (int d = 16 * half; d < 16 * half + 16; ++d) p[r][d] *= scl;
    }
    __syncthreads();

    // ================= Phase C: logits + softmax -> S in scratch =================
    const float sc_h = __expf(fminf(logit_scale[hh], kMaxLogit));
    float4 qv[8];
#pragma unroll
    for (int d4 = 0; d4 < 8; ++d4) qv[d4] = *(const float4*)(&s_q[n][d4 * 4]);
    float p8[8];
    float mx = -1e30f;
    // unroll 2: full unroll hoists 8x8 float4 k-row reads -> spill
#pragma unroll 2
    for (int j = 0; j < 8; ++j) {
      const int m = ms + 8 * j;  // stride-8 map: k-row LDS addrs spread over banks
      float a = 0.f;
#pragma unroll
      for (int d4 = 0; d4 < 8; ++d4) a += dot4(qv[d4], *(const float4*)(&s_k[m][d4 * 4]));
      a = fmaf(a, sc_h, mask[(size_t)win * 4096 + n * 64 + m]);
      p8[j] = a;
      mx = fmaxf(mx, a);
    }
    mx = fmaxf(mx, __shfl_xor(mx, 1));
    mx = fmaxf(mx, __shfl_xor(mx, 2));
    mx = fmaxf(mx, __shfl_xor(mx, 4));
    float sm = 0.f;
#pragma unroll
    for (int j = 0; j < 8; ++j) { p8[j] = __expf(p8[j] - mx); sm += p8[j]; }
    sm += __shfl_xor(sm, 1);
    sm += __shfl_xor(sm, 2);
    sm += __shfl_xor(sm, 4);
    const float rinv = 1.0f / sm;
#pragma unroll
    for (int j = 0; j < 8; ++j) s_scr[n * 68 + ms + 8 * j] = p8[j] * rinv;
    __syncthreads();

    // ================= Phase D: attn_h = P @ V  (result -> s_q) =================
    float4 o4 = {0.f, 0.f, 0.f, 0.f};
    // unroll 4: full unroll hoists 16x5 float4 (~320 VGPRs) -> spill
#pragma unroll 4
    for (int m4 = 0; m4 < 16; ++m4) {
      const float4 pv = *(const float4*)(&s_scr[n * 68 + m4 * 4]);
      const float4 v0 = *(const float4*)(&s_v[m4 * 4 + 0][d0]);
      const float4 v1 = *(const float4*)(&s_v[m4 * 4 + 1][d0]);
      const float4 v2 = *(const float4*)(&s_v[m4 * 4 + 2][d0]);
      const float4 v3 = *(const float4*)(&s_v[m4 * 4 + 3][d0]);
      o4.x = fmaf(pv.x, v0.x, o4.x); o4.y = fmaf(pv.x, v0.y, o4.y); o4.z = fmaf(pv.x, v0.z, o4.z); o4.w = fmaf(pv.x, v0.w, o4.w);
      o4.x = fmaf(pv.y, v1.x, o4.x); o4.y = fmaf(pv.y, v1.y, o4.y); o4.z = fmaf(pv.y, v1.z, o4.z); o4.w = fmaf(pv.y, v1.w, o4.w);
      o4.x = fmaf(pv.z, v2.x, o4.x); o4.y = fmaf(pv.z, v2.y, o4.y); o4.z = fmaf(pv.z, v2.z, o4.z); o4.w = fmaf(pv.z, v2.w, o4.w);
      o4.x = fmaf(pv.w, v3.x, o4.x); o4.y = fmaf(pv.w, v3.y, o4.y); o4.z = fmaf(pv.w, v3.z, o4.z); o4.w = fmaf(pv.w, v3.w, o4.w);
    }
    *(float4*)(&s_q[n][d0]) = o4;  // s_q now holds attn_h
    __syncthreads();

    // ================= Phase E: out += attn_h @ proj_w[:, head]^T =================
    for (int dc = 0; dc < 2; ++dc) {
      __syncthreads();  // prior scratch readers done (dc=0: phase D; dc=1: previous chunk)
      for (int m = tid; m < 1024; m += NT) {
        const int c = m >> 2, dd4 = m & 3;
        const float4 v = *(const float4*)(proj_w + (size_t)c * 256 + hh * 32 + dc * 16 + dd4 * 4);
        s_scr[(dd4 * 4 + 0) * 256 + c] = v.x;
        s_scr[(dd4 * 4 + 1) * 256 + c] = v.y;
        s_scr[(dd4 * 4 + 2) * 256 + c] = v.z;
        s_scr[(dd4 * 4 + 3) * 256 + c] = v.w;
      }
      __syncthreads();
      // unroll 2: cap hoisted a4/wlo/whi fronts
#pragma unroll 2
      for (int d4 = 0; d4 < 4; ++d4) {
        float4 a4[4];
#pragma unroll
        for (int i = 0; i < 4; ++i) a4[i] = *(const float4*)(&s_q[4 * rg + i][dc * 16 + d4 * 4]);
#pragma unroll
        for (int kk = 0; kk < 4; ++kk) {
          const int dd = d4 * 4 + kk;
          const float4 wlo = *(const float4*)(&s_scr[dd * 256 + 4 * cg]);
          const float4 whi = *(const float4*)(&s_scr[dd * 256 + 128 + 4 * cg]);
#pragma unroll
          for (int i = 0; i < 4; ++i) {
            const float av = (kk == 0) ? a4[i].x : (kk == 1) ? a4[i].y : (kk == 2) ? a4[i].z : a4[i].w;
            accE[i][0] = fmaf(av, wlo.x, accE[i][0]);
            accE[i][1] = fmaf(av, wlo.y, accE[i][1]);
            accE[i][2] = fmaf(av, wlo.z, accE[i][2]);
            accE[i][3] = fmaf(av, wlo.w, accE[i][3]);
            accE[i][4] = fmaf(av, whi.x, accE[i][4]);
            accE[i][5] = fmaf(av, whi.y, accE[i][5]);
            accE[i][6] = fmaf(av, whi.z, accE[i][6]);
            accE[i][7] = fmaf(av, whi.w, accE[i][7]);
          }
        }
      }
    }
    __syncthreads();  // end-of-head fence before next phase A overwrites LDS
  }

  // ---- final store (fully overwrites d_out) ----
  float* ob = out + (size_t)b * (kN * kC);
#pragma unroll
  for (int i = 0; i < 4; ++i) {
    const float4 lo = {accE[i][0], accE[i][1], accE[i][2], accE[i][3]};
    const float4 hi = {accE[i][4], accE[i][5], accE[i][6], accE[i][7]};
    *(float4*)(&ob[(4 * rg + i) * 256 + 4 * cg]) = lo;
    *(float4*)(&ob[(4 * rg + i) * 256 + 128 + 4 * cg]) = hi;
  }
}

}  // namespace

extern "C" void kernel_launch(void* const* d_in, const int* in_sizes, int n_in,
                              void* d_out, int out_size, void* d_ws, size_t ws_size,
                              hipStream_t stream) {
  (void)n_in; (void)d_ws; (void)ws_size; (void)out_size;
  const float* x = (const float*)d_in[0];
  const float* mask = (const float*)d_in[1];
  const float* qkv_w = (const float*)d_in[2];
  const float* qkv_b = (const float*)d_in[3];
  const float* proj_w = (const float*)d_in[4];
  const float* proj_b = (const float*)d_in[5];
  const float* lsc = (const float*)d_in[6];
  float* out = (float*)d_out;

  const int nB = in_sizes[0] / (kN * kC);  // 4096
  dim3 grid(nB), block(NT);
  hipLaunchKernelGGL(fused_window_attn, grid, block, 0, stream,
                     x, mask, qkv_w, qkv_b, proj_w, proj_b, lsc, out);
}

// Round 5
// 2196.329 us; speedup vs baseline: 22.1064x; 2.3695x over previous
//
#include <hip/hip_runtime.h>
#include <cmath>

// Fused window attention w/ view-aware RoPE. One block per window
// (B=4096 blocks, 512 threads = 8 waves). Zero workspace.
//
// R1-R4: spill elimination arc (64->128->cap+unroll fixes): 48.5->5.2ms.
//        R4 counters: WRITE=output only, HBM 2.4%, VALUBusy 52%, LDS-read
//        cycles ~2x FMA cycles -> co-bound on LDS BW + VALU + barriers.
// R5: phase A (qkv GEMM, 60% of FLOPs, worst LDS phase) -> MFMA bf16x3
//     split (x=hi+lo; x*w ~ hh+hl+lh, fp32 accum, ~2^-16 rel err).
//     x converted to split-bf16 LDS ONCE per block (kills the 8x global
//     x re-reads too). Phases B-E unchanged. LDS 148KB (fits 160KB;
//     occupancy was already 1 block/CU).

namespace {

constexpr int kN = 64;    // tokens per window
constexpr int kC = 256;   // channels
constexpr int kH = 8;     // heads
constexpr float kMaxLogit = 4.6051701859880913680f;  // log(100)
constexpr int NT = 512;

typedef __attribute__((ext_vector_type(8))) short bf16x8;
typedef __attribute__((ext_vector_type(4))) float f32x4;

__device__ __forceinline__ float dot4(const float4 a, const float4 b) {
  return fmaf(a.x, b.x, fmaf(a.y, b.y, fmaf(a.z, b.z, a.w * b.w)));
}

__device__ __forceinline__ unsigned short f2bf(float f) {
  union { float f; unsigned int u; } v; v.f = f;
  return (unsigned short)((v.u + 0x7FFFu + ((v.u >> 16) & 1u)) >> 16);
}
__device__ __forceinline__ float bf2f(unsigned short h) {
  union { unsigned int u; float f; } v; v.u = ((unsigned int)h) << 16;
  return v.f;
}

__global__ __launch_bounds__(NT, 1) void fused_window_attn(
    const float* __restrict__ x, const float* __restrict__ mask,
    const float* __restrict__ qkv_w, const float* __restrict__ qkv_b,
    const float* __restrict__ proj_w, const float* __restrict__ proj_b,
    const float* __restrict__ logit_scale, float* __restrict__ out) {

  // split-bf16 x block (staged once). 264 = 256+8 pad: row stride 528B =
  // 33*16B -> b128 frag reads land ~2-way on banks (free, m136).
  __shared__ unsigned short s_xh[64][264];
  __shared__ unsigned short s_xl[64][264];
  // split-bf16 weight chunk (per head, per k-chunk of 64). 72 = 64+8 pad.
  __shared__ unsigned short s_wh[96][72];
  __shared__ unsigned short s_wl[96][72];
  __shared__ float s_q[64][36];
  __shared__ float s_k[64][36];
  __shared__ float s_v[64][36];
  __shared__ float s_cs[64][16];
  __shared__ float s_sn[64][16];
  __shared__ float s_scr[64 * 68];  // union: S[64][68]=4352 | pwT[16][256]=4096

  const int b = blockIdx.x;
  const int tid = threadIdx.x;
  const int win = b & 63;  // b = g*64 + w  ->  mask window index
  const float* xb = x + (size_t)b * (kN * kC);

  const int cg = tid & 31;  // phase E: col quad
  const int rg = tid >> 5;  // 16 groups of 4 rows

  // MFMA wave geometry: 8 waves cover 64 rows x 96 cols as 4x2 super-tiles
  // of 16 rows x 48 cols (3 col-tiles of 16).
  const int lane = tid & 63;
  const int wv = tid >> 6;
  const int rt = wv >> 1;            // row-tile 0..3 (16 rows each)
  const int cbase = (wv & 1) * 48;   // col base 0 or 48
  const int lrow = lane & 15;        // frag row/col index
  const int lk8 = (lane >> 4) * 8;   // frag k offset

  // ---- output accumulators (rows 4rg+i, cols {4cg+j, 128+4cg+j}), init = bias ----
  float accE[4][8];
  {
    const float4 blo = *(const float4*)(proj_b + 4 * cg);
    const float4 bhi = *(const float4*)(proj_b + 128 + 4 * cg);
#pragma unroll
    for (int i = 0; i < 4; ++i) {
      accE[i][0] = blo.x; accE[i][1] = blo.y; accE[i][2] = blo.z; accE[i][3] = blo.w;
      accE[i][4] = bhi.x; accE[i][5] = bhi.y; accE[i][6] = bhi.z; accE[i][7] = bhi.w;
    }
  }

  // ---- stage x block as split bf16 (once per block) ----
#pragma unroll
  for (int it = 0; it < 8; ++it) {
    const int m = tid + it * NT;          // 4096 quad-tasks
    const int r = m >> 6, kq = m & 63;
    const float4 xv = *(const float4*)(xb + r * kC + kq * 4);
    ushort4 h, l;
    h.x = f2bf(xv.x); h.y = f2bf(xv.y); h.z = f2bf(xv.z); h.w = f2bf(xv.w);
    l.x = f2bf(xv.x - bf2f(h.x)); l.y = f2bf(xv.y - bf2f(h.y));
    l.z = f2bf(xv.z - bf2f(h.z)); l.w = f2bf(xv.w - bf2f(h.w));
    *(ushort4*)(&s_xh[r][kq * 4]) = h;
    *(ushort4*)(&s_xl[r][kq * 4]) = l;
  }

  // ---- rope tables: angle = (n + VIEW_ID*VIEW_OFFSET) * 10000^(-i/16) ----
  for (int it = tid; it < 64 * 16; it += NT) {
    const int r = it >> 4, ii = it & 15;
    const float inv = expf(-0.575646273248511421f * (float)ii);  // log(10000)/16
    const float ang = ((float)r + 0.1f) * inv;
    s_cs[r][ii] = cosf(ang);
    s_sn[r][ii] = sinf(ang);
  }
  __syncthreads();

  const int n = tid >> 3;   // phase C/D row
  const int ms = tid & 7;   // phase C col-slot
  const int d0 = (tid & 7) * 4;  // phase D dim quad

  for (int hh = 0; hh < kH; ++hh) {
    // ========== Phase A: qkv = x @ Wqkv[head]^T via MFMA bf16x3 ==========
    f32x4 accA[3];
#pragma unroll
    for (int t = 0; t < 3; ++t) accA[t] = (f32x4){0.f, 0.f, 0.f, 0.f};

    for (int kc = 0; kc < 4; ++kc) {   // k chunks of 64
      __syncthreads();  // staging buffer reuse fence
      // stage 96 weight rows x 64-k chunk as split bf16
#pragma unroll
      for (int it = 0; it < 3; ++it) {
        const int m = tid + it * NT;          // 1536 quad-tasks
        const int wr = m >> 4, kq = m & 15;
        const int comp = wr >> 5, dim = wr & 31;
        const float4 wv = *(const float4*)(qkv_w +
            ((size_t)(comp * 256 + hh * 32 + dim) * 256 + kc * 64 + kq * 4));
        ushort4 h, l;
        h.x = f2bf(wv.x); h.y = f2bf(wv.y); h.z = f2bf(wv.z); h.w = f2bf(wv.w);
        l.x = f2bf(wv.x - bf2f(h.x)); l.y = f2bf(wv.y - bf2f(h.y));
        l.z = f2bf(wv.z - bf2f(h.z)); l.w = f2bf(wv.w - bf2f(h.w));
        *(ushort4*)(&s_wh[wr][kq * 4]) = h;
        *(ushort4*)(&s_wl[wr][kq * 4]) = l;
      }
      __syncthreads();
#pragma unroll
      for (int ks = 0; ks < 2; ++ks) {  // two K=32 MFMA steps per chunk
        const int ko = ks * 32 + lk8;
        const bf16x8 ah = *(const bf16x8*)(&s_xh[rt * 16 + lrow][kc * 64 + ko]);
        const bf16x8 al = *(const bf16x8*)(&s_xl[rt * 16 + lrow][kc * 64 + ko]);
#pragma unroll
        for (int t = 0; t < 3; ++t) {
          const bf16x8 bh = *(const bf16x8*)(&s_wh[cbase + t * 16 + lrow][ko]);
          const bf16x8 bl = *(const bf16x8*)(&s_wl[cbase + t * 16 + lrow][ko]);
          accA[t] = __builtin_amdgcn_mfma_f32_16x16x32_bf16(al, bh, accA[t], 0, 0, 0);
          accA[t] = __builtin_amdgcn_mfma_f32_16x16x32_bf16(ah, bl, accA[t], 0, 0, 0);
          accA[t] = __builtin_amdgcn_mfma_f32_16x16x32_bf16(ah, bh, accA[t], 0, 0, 0);
        }
      }
    }
    // epilogue: bias + park q/k/v in fp32 LDS. C-frag: col=lane&15,
    // row=(lane>>4)*4+j (m89-verified). Tiles never straddle components.
#pragma unroll
    for (int t = 0; t < 3; ++t) {
      const int col = cbase + t * 16;
      const int comp = col >> 5;
      const int dim = (col & 31) + lrow;
      const float bias = qkv_b[comp * 256 + hh * 32 + dim];
      float (*dst)[36] = (comp == 0) ? s_q : (comp == 1) ? s_k : s_v;
#pragma unroll
      for (int j = 0; j < 4; ++j)
        dst[rt * 16 + (lane >> 4) * 4 + j][dim] = accA[t][j] + bias;
    }
    __syncthreads();

    // ================= Phase B: RoPE (half-split) + L2 normalize =================
    for (int it = tid; it < 2048; it += NT) {
      const int buf = it >> 10;
      const int r = (it >> 4) & 63;
      const int ii = it & 15;
      float (*p)[36] = buf ? s_k : s_q;
      const float a = p[r][ii], b2 = p[r][ii + 16];
      const float c = s_cs[r][ii], s = s_sn[r][ii];
      p[r][ii] = a * c - b2 * s;
      p[r][ii + 16] = a * s + b2 * c;
    }
    __syncthreads();
    if (tid < 256) {
      const int rt2 = tid >> 1, half = tid & 1;
      float (*p)[36] = (rt2 >= 64) ? s_k : s_q;
      const int r = rt2 & 63;
      float ss = 0.f;
#pragma unroll
      for (int d = 16 * half; d < 16 * half + 16; ++d) ss = fmaf(p[r][d], p[r][d], ss);
      ss += __shfl_xor(ss, 1);
      const float scl = 1.0f / fmaxf(sqrtf(ss), 1e-12f);
#pragma unroll
      for (int d = 16 * half; d < 16 * half + 16; ++d) p[r][d] *= scl;
    }
    __syncthreads();

    // ================= Phase C: logits + softmax -> S in scratch =================
    const float sc_h = __expf(fminf(logit_scale[hh], kMaxLogit));
    float4 qv[8];
#pragma unroll
    for (int d4 = 0; d4 < 8; ++d4) qv[d4] = *(const float4*)(&s_q[n][d4 * 4]);
    float p8[8];
    float mx = -1e30f;
    // unroll 2: full unroll hoists 8x8 float4 k-row reads -> spill
#pragma unroll 2
    for (int j = 0; j < 8; ++j) {
      const int m = ms + 8 * j;  // stride-8 map: k-row LDS addrs spread over banks
      float a = 0.f;
#pragma unroll
      for (int d4 = 0; d4 < 8; ++d4) a += dot4(qv[d4], *(const float4*)(&s_k[m][d4 * 4]));
      a = fmaf(a, sc_h, mask[(size_t)win * 4096 + n * 64 + m]);
      p8[j] = a;
      mx = fmaxf(mx, a);
    }
    mx = fmaxf(mx, __shfl_xor(mx, 1));
    mx = fmaxf(mx, __shfl_xor(mx, 2));
    mx = fmaxf(mx, __shfl_xor(mx, 4));
    float sm = 0.f;
#pragma unroll
    for (int j = 0; j < 8; ++j) { p8[j] = __expf(p8[j] - mx); sm += p8[j]; }
    sm += __shfl_xor(sm, 1);
    sm += __shfl_xor(sm, 2);
    sm += __shfl_xor(sm, 4);
    const float rinv = 1.0f / sm;
#pragma unroll
    for (int j = 0; j < 8; ++j) s_scr[n * 68 + ms + 8 * j] = p8[j] * rinv;
    __syncthreads();

    // ================= Phase D: attn_h = P @ V  (result -> s_q) =================
    float4 o4 = {0.f, 0.f, 0.f, 0.f};
    // unroll 4: full unroll hoists 16x5 float4 (~320 VGPRs) -> spill
#pragma unroll 4
    for (int m4 = 0; m4 < 16; ++m4) {
      const float4 pv = *(const float4*)(&s_scr[n * 68 + m4 * 4]);
      const float4 v0 = *(const float4*)(&s_v[m4 * 4 + 0][d0]);
      const float4 v1 = *(const float4*)(&s_v[m4 * 4 + 1][d0]);
      const float4 v2 = *(const float4*)(&s_v[m4 * 4 + 2][d0]);
      const float4 v3 = *(const float4*)(&s_v[m4 * 4 + 3][d0]);
      o4.x = fmaf(pv.x, v0.x, o4.x); o4.y = fmaf(pv.x, v0.y, o4.y); o4.z = fmaf(pv.x, v0.z, o4.z); o4.w = fmaf(pv.x, v0.w, o4.w);
      o4.x = fmaf(pv.y, v1.x, o4.x); o4.y = fmaf(pv.y, v1.y, o4.y); o4.z = fmaf(pv.y, v1.z, o4.z); o4.w = fmaf(pv.y, v1.w, o4.w);
      o4.x = fmaf(pv.z, v2.x, o4.x); o4.y = fmaf(pv.z, v2.y, o4.y); o4.z = fmaf(pv.z, v2.z, o4.z); o4.w = fmaf(pv.z, v2.w, o4.w);
      o4.x = fmaf(pv.w, v3.x, o4.x); o4.y = fmaf(pv.w, v3.y, o4.y); o4.z = fmaf(pv.w, v3.z, o4.z); o4.w = fmaf(pv.w, v3.w, o4.w);
    }
    *(float4*)(&s_q[n][d0]) = o4;  // s_q now holds attn_h
    __syncthreads();

    // ================= Phase E: out += attn_h @ proj_w[:, head]^T =================
    for (int dc = 0; dc < 2; ++dc) {
      __syncthreads();  // prior scratch readers done (dc=0: phase D; dc=1: previous chunk)
      for (int m = tid; m < 1024; m += NT) {
        const int c = m >> 2, dd4 = m & 3;
        const float4 v = *(const float4*)(proj_w + (size_t)c * 256 + hh * 32 + dc * 16 + dd4 * 4);
        s_scr[(dd4 * 4 + 0) * 256 + c] = v.x;
        s_scr[(dd4 * 4 + 1) * 256 + c] = v.y;
        s_scr[(dd4 * 4 + 2) * 256 + c] = v.z;
        s_scr[(dd4 * 4 + 3) * 256 + c] = v.w;
      }
      __syncthreads();
      // unroll 2: cap hoisted a4/wlo/whi fronts
#pragma unroll 2
      for (int d4 = 0; d4 < 4; ++d4) {
        float4 a4[4];
#pragma unroll
        for (int i = 0; i < 4; ++i) a4[i] = *(const float4*)(&s_q[4 * rg + i][dc * 16 + d4 * 4]);
#pragma unroll
        for (int kk = 0; kk < 4; ++kk) {
          const int dd = d4 * 4 + kk;
          const float4 wlo = *(const float4*)(&s_scr[dd * 256 + 4 * cg]);
          const float4 whi = *(const float4*)(&s_scr[dd * 256 + 128 + 4 * cg]);
#pragma unroll
          for (int i = 0; i < 4; ++i) {
            const float av = (kk == 0) ? a4[i].x : (kk == 1) ? a4[i].y : (kk == 2) ? a4[i].z : a4[i].w;
            accE[i][0] = fmaf(av, wlo.x, accE[i][0]);
            accE[i][1] = fmaf(av, wlo.y, accE[i][1]);
            accE[i][2] = fmaf(av, wlo.z, accE[i][2]);
            accE[i][3] = fmaf(av, wlo.w, accE[i][3]);
            accE[i][4] = fmaf(av, whi.x, accE[i][4]);
            accE[i][5] = fmaf(av, whi.y, accE[i][5]);
            accE[i][6] = fmaf(av, whi.z, accE[i][6]);
            accE[i][7] = fmaf(av, whi.w, accE[i][7]);
          }
        }
      }
    }
    __syncthreads();  // end-of-head fence before next phase A overwrites LDS
  }

  // ---- final store (fully overwrites d_out) ----
  float* ob = out + (size_t)b * (kN * kC);
#pragma unroll
  for (int i = 0; i < 4; ++i) {
    const float4 lo = {accE[i][0], accE[i][1], accE[i][2], accE[i][3]};
    const float4 hi = {accE[i][4], accE[i][5], accE[i][6], accE[i][7]};
    *(float4*)(&ob[(4 * rg + i) * 256 + 4 * cg]) = lo;
    *(float4*)(&ob[(4 * rg + i) * 256 + 128 + 4 * cg]) = hi;
  }
}

}  // namespace

extern "C" void kernel_launch(void* const* d_in, const int* in_sizes, int n_in,
                              void* d_out, int out_size, void* d_ws, size_t ws_size,
                              hipStream_t stream) {
  (void)n_in; (void)d_ws; (void)ws_size; (void)out_size;
  const float* x = (const float*)d_in[0];
  const float* mask = (const float*)d_in[1];
  const float* qkv_w = (const float*)d_in[2];
  const float* qkv_b = (const float*)d_in[3];
  const float* proj_w = (const float*)d_in[4];
  const float* proj_b = (const float*)d_in[5];
  const float* lsc = (const float*)d_in[6];
  float* out = (float*)d_out;

  const int nB = in_sizes[0] / (kN * kC);  // 4096
  dim3 grid(nB), block(NT);
  hipLaunchKernelGGL(fused_window_attn, grid, block, 0, stream,
                     x, mask, qkv_w, qkv_b, proj_w, proj_b, lsc, out);
}